// Round 3
// baseline (22.929 us; speedup 1.0000x reference)
//
#include <hip/hip_runtime.h>

// Routed embedding-bag sum-pool. One block (128 threads) per bag.
//   Phase 1: resolve up to 128 token row pointers into LDS.
//   Phase 2: 4 groups of 32 lanes; lane reads float4 -> 32 lanes = one 512B row.
//            Fast path for cnt==50 (the uniform bag length): hoist all 13
//            pointers to registers, fully unroll -> up to 13 loads in flight.
//   Phase 3: LDS reduction across the 4 groups.

#define TOK_CHUNK 128
#define EMB_D 128

__global__ __launch_bounds__(EMB_D)
void embbag_kernel(const int* __restrict__ qr,
                   const int* __restrict__ offsets,
                   const float* __restrict__ hot_W,
                   const float* __restrict__ hash_W,
                   float* __restrict__ out,
                   int N, int B, int hot_rows, int hash_rows) {
    const int b   = blockIdx.x;
    const int tid = threadIdx.x;   // 0..127
    const int g   = tid >> 5;      // token group 0..3
    const int c   = tid & 31;      // dim-quad index 0..31
    const int start = offsets[b];
    const int end   = (b + 1 < B) ? offsets[b + 1] : N;

    __shared__ const float* rows[TOK_CHUNK];
    __shared__ float red[4][EMB_D];

    float4 acc = {0.0f, 0.0f, 0.0f, 0.0f};
    for (int base = start; base < end; base += TOK_CHUNK) {
        const int cnt = min(TOK_CHUNK, end - base);
        if (tid < cnt) {
            const int q = qr[base + tid];
            const float* r;
            if (q < 0) {
                int hi = -q;                     // 1 .. HOT
                const int mx = hot_rows - 1;     // clip
                if (hi > mx) hi = mx;
                r = hot_W + (size_t)hi * EMB_D;
            } else {
                r = hash_W + (size_t)(q % hash_rows) * EMB_D;
            }
            rows[tid] = r;
        }
        __syncthreads();

        if (cnt == 50) {
            // Uniform-bag fast path: tokens g, g+4, ... ; g<2 -> 13, else 12.
            const int nt = (g < 2) ? 13 : 12;        // wave-uniform
            const float* p[13];
            #pragma unroll
            for (int k = 0; k < 13; ++k) {
                const int t = g + 4 * k;
                p[k] = rows[(t < 50) ? t : g];       // safe dummy for inactive
            }
            float4 a0 = {0.f,0.f,0.f,0.f}, a1 = {0.f,0.f,0.f,0.f};
            #pragma unroll
            for (int k = 0; k < 13; ++k) {
                if (k < nt) {
                    const float4 v = *(const float4*)(p[k] + c * 4);
                    if (k & 1) { a1.x += v.x; a1.y += v.y; a1.z += v.z; a1.w += v.w; }
                    else       { a0.x += v.x; a0.y += v.y; a0.z += v.z; a0.w += v.w; }
                }
            }
            acc.x += a0.x + a1.x; acc.y += a0.y + a1.y;
            acc.z += a0.z + a1.z; acc.w += a0.w + a1.w;
        } else {
            #pragma unroll 4
            for (int t = g; t < cnt; t += 4) {
                const float4 v = *(const float4*)(rows[t] + c * 4);
                acc.x += v.x; acc.y += v.y; acc.z += v.z; acc.w += v.w;
            }
        }
        __syncthreads();
    }

    // reduce the 4 token-groups' partials
    *(float4*)&red[g][c * 4] = acc;
    __syncthreads();
    const float s = red[0][tid] + red[1][tid] + red[2][tid] + red[3][tid];
    out[(size_t)b * EMB_D + tid] = s;
}

extern "C" void kernel_launch(void* const* d_in, const int* in_sizes, int n_in,
                              void* d_out, int out_size, void* d_ws, size_t ws_size,
                              hipStream_t stream) {
    // setup_inputs order: feature_ids, offsets, query_results, hot_W, hash_W
    const int*   offsets = (const int*)d_in[1];
    const int*   qr      = (const int*)d_in[2];
    const float* hot_W   = (const float*)d_in[3];
    const float* hash_W  = (const float*)d_in[4];
    float*       out     = (float*)d_out;

    const int N         = in_sizes[0];
    const int B         = in_sizes[1];
    const int hot_rows  = in_sizes[3] / EMB_D;
    const int hash_rows = in_sizes[4] / EMB_D;

    embbag_kernel<<<B, EMB_D, 0, stream>>>(qr, offsets, hot_W, hash_W, out,
                                           N, B, hot_rows, hash_rows);
}